// Round 5
// baseline (373.965 us; speedup 1.0000x reference)
//
#include <hip/hip_runtime.h>

#define DD 128
#define SCAN_CHUNK 2048   // 256 threads x 8 elements per scan block
#define PAD1 16           // cnt1 stride: one counter per 64B line
#define PAD2 8            // cnt2 stride: two counters per 64B line

typedef __attribute__((ext_vector_type(8))) _Float16 f16x8;
typedef __attribute__((ext_vector_type(4))) _Float16 f16x4;
typedef __attribute__((ext_vector_type(4))) float f32x4;
typedef __attribute__((ext_vector_type(4))) int i32x4;

template <typename T>
__device__ __forceinline__ T ntl(const T* p) { return __builtin_nontemporal_load(p); }
template <typename T>
__device__ __forceinline__ void nts(T v, T* p) { __builtin_nontemporal_store(v, p); }

// ---------------------------------------------------------------------------
// k_hist1: three block ranges, all independent:
//   [0, hb)        : histogram g1 into padded counters, capture ranks
//   [hb, hb+8)     : fold (1-b)I + b*W into fp16 M' (prep_w)
//   [hb+8, +cb)    : convert X (fp32) -> Xh (fp16), all NT (pure stream)
// ---------------------------------------------------------------------------
__global__ __launch_bounds__(256)
void k_hist1(const int* __restrict__ g1d, int* __restrict__ cnt1p,
             int* __restrict__ rank1, int nnz, int no, int hb,
             const float* __restrict__ W, const float* __restrict__ betaP,
             _Float16* __restrict__ Mh,
             const float* __restrict__ X, _Float16* __restrict__ Xh, int nx) {
    const int b = blockIdx.x;
    if (b < hb) {                              // ---- hist g1 ----
        int q = b * 256 + threadIdx.x;
        if (q >= no) return;
        int i = q << 3;
        if (i + 8 <= nnz) {
            i32x4 d0 = ntl((const i32x4*)(g1d + i));
            i32x4 d1 = ntl((const i32x4*)(g1d + i + 4));
            i32x4 ra, rb;
            ra[0] = atomicAdd(&cnt1p[d0[0] * PAD1], 1);
            ra[1] = atomicAdd(&cnt1p[d0[1] * PAD1], 1);
            ra[2] = atomicAdd(&cnt1p[d0[2] * PAD1], 1);
            ra[3] = atomicAdd(&cnt1p[d0[3] * PAD1], 1);
            rb[0] = atomicAdd(&cnt1p[d1[0] * PAD1], 1);
            rb[1] = atomicAdd(&cnt1p[d1[1] * PAD1], 1);
            rb[2] = atomicAdd(&cnt1p[d1[2] * PAD1], 1);
            rb[3] = atomicAdd(&cnt1p[d1[3] * PAD1], 1);
            nts(ra, (i32x4*)(rank1 + i));
            nts(rb, (i32x4*)(rank1 + i + 4));
        } else {
            for (; i < nnz; ++i) rank1[i] = atomicAdd(&cnt1p[g1d[i] * PAD1], 1);
        }
        return;
    }
    if (b < hb + 8) {                          // ---- prep_w (fp16 M') ----
        int gid = (b - hb) * 256 + threadIdx.x;     // 2048 threads, 8 elems each
        if (gid >= DD * DD / 8) return;
        int c  = gid >> 4;
        int k0 = (gid & 15) << 3;
        float bb = betaP[0], ib = 1.0f - bb;
        const float* p = W + c * DD + k0;
        f32x4 lo = *(const f32x4*)p, hi = *(const f32x4*)(p + 4);
        float v[8] = {lo[0], lo[1], lo[2], lo[3], hi[0], hi[1], hi[2], hi[3]};
        f16x8 t;
        #pragma unroll
        for (int j = 0; j < 8; ++j) {
            float m = bb * v[j] + ((k0 + j) == c ? ib : 0.0f);
            t[j] = (_Float16)m;
        }
        *(f16x8*)(Mh + (size_t)c * DD + k0) = t;
        return;
    }
    // ---- X -> fp16 conversion (pure stream: NT both sides) ----
    int gid = (b - hb - 8) * 256 + threadIdx.x;
    int i = gid << 3;
    if (i + 8 <= nx) {
        f32x4 lo = ntl((const f32x4*)(X + i));
        f32x4 hi = ntl((const f32x4*)(X + i + 4));
        f16x8 t;
        t[0] = (_Float16)lo[0]; t[1] = (_Float16)lo[1];
        t[2] = (_Float16)lo[2]; t[3] = (_Float16)lo[3];
        t[4] = (_Float16)hi[0]; t[5] = (_Float16)hi[1];
        t[6] = (_Float16)hi[2]; t[7] = (_Float16)hi[3];
        nts(t, (f16x8*)(Xh + i));
    } else {
        for (; i < nx; ++i) Xh[i] = (_Float16)X[i];
    }
}

// ---------------------------------------------------------------------------
// k_scan_blocks: chunk-local EXCLUSIVE scan of padded counters -> off[]
// (chunk-local values only; consumers add the chunk base from bsum),
// per-chunk totals -> bsum[b]. Stores off[idx] for idx <= n so off[n] exists.
// ---------------------------------------------------------------------------
__global__ __launch_bounds__(256)
void k_scan_blocks(const int* __restrict__ cnt, int* __restrict__ off,
                   int* __restrict__ bsum, int n, int str) {
    __shared__ int sh[256];
    const int tid = threadIdx.x;
    const int base = blockIdx.x * SCAN_CHUNK + tid * 8;
    int v[8];
    int s = 0;
    #pragma unroll
    for (int j = 0; j < 8; ++j) {
        int idx = base + j;
        v[j] = (idx < n) ? cnt[(size_t)idx * str] : 0;
        s += v[j];
    }
    sh[tid] = s;
    __syncthreads();
    for (int d = 1; d < 256; d <<= 1) {
        int y = (tid >= d) ? sh[tid - d] : 0;
        __syncthreads();
        sh[tid] += y;
        __syncthreads();
    }
    int incl = sh[tid];
    int run = incl - s;
    #pragma unroll
    for (int j = 0; j < 8; ++j) {
        int idx = base + j;
        if (idx <= n) off[idx] = run;
        run += v[j];
    }
    if (tid == 255) bsum[blockIdx.x] = incl;      // chunk total (inclusive)
}

// ---------------------------------------------------------------------------
// load bsum in parallel, LDS-only serial scan (nb <= 49): no serial global
// latency chain (was ~49 x ~500cy of thread-0 stalls per block).
// ---------------------------------------------------------------------------
__device__ __forceinline__ void lds_pref(int* pref, const int* bsum, int nb,
                                         int tid) {
    if (tid < 64) pref[tid] = (tid < nb) ? bsum[tid] : 0;
    __syncthreads();
    if (tid == 0) {
        int run = 0;
        for (int i = 0; i < nb; ++i) { int t = pref[i]; pref[i] = run; run += t; }
        pref[nb] = run;
    }
    __syncthreads();
}

// ---------------------------------------------------------------------------
// k_fill: srcs[off[d] + pref[d>>11] + rank[i]] = src[i]. No atomics.
// ---------------------------------------------------------------------------
__global__ __launch_bounds__(256)
void k_fill(const int* __restrict__ dst, const int* __restrict__ src,
            const int* __restrict__ off, const int* __restrict__ rank,
            const int* __restrict__ bsum, int nb,
            int* __restrict__ out, int nnz) {
    __shared__ int pref[65];
    lds_pref(pref, bsum, nb, threadIdx.x);
    int q = blockIdx.x * 256 + threadIdx.x;
    int i = q << 2;
    if (i + 4 <= nnz) {
        i32x4 d = ntl((const i32x4*)(dst + i));
        i32x4 s = ntl((const i32x4*)(src + i));
        i32x4 r = ntl((const i32x4*)(rank + i));
        int o0 = off[d[0]] + pref[d[0] >> 11];
        int o1 = off[d[1]] + pref[d[1] >> 11];
        int o2 = off[d[2]] + pref[d[2] >> 11];
        int o3 = off[d[3]] + pref[d[3] >> 11];
        out[o0 + r[0]] = s[0];
        out[o1 + r[1]] = s[1];
        out[o2 + r[2]] = s[2];
        out[o3 + r[3]] = s[3];
    } else {
        for (; i < nnz; ++i)
            out[off[dst[i]] + pref[dst[i] >> 11] + rank[i]] = src[i];
    }
}

// ---------------------------------------------------------------------------
// k_h2_egather: fused kernel.
//   blocks [0,H):  histogram g2 (atomic/latency-bound, no upstream deps)
//   blocks [H,..): edge gather, one wave per edge: lanes = 4 refs x 16
//                  column-groups; shfl_xor(16/32) reduce; group 0 writes row.
// NT on all streams (indices, ranks, output row); Xh gather stays cacheable.
// ---------------------------------------------------------------------------
__global__ __launch_bounds__(256)
void k_h2_egather(const int* __restrict__ g2d, int* __restrict__ cnt2p,
                  int* __restrict__ rank2, int nnz, int no, int H,
                  const _Float16* __restrict__ Xh, const int* __restrict__ off1,
                  const int* __restrict__ bsum1, int nb1,
                  const int* __restrict__ srcs1, const float* __restrict__ degE,
                  _Float16* __restrict__ XeH, int n_edges) {
    if (blockIdx.x < H) {                         // ---- hist g2 path ----
        int q = blockIdx.x * 256 + threadIdx.x;
        if (q >= no) return;
        int i = q << 3;
        if (i + 8 <= nnz) {
            i32x4 d0 = ntl((const i32x4*)(g2d + i));
            i32x4 d1 = ntl((const i32x4*)(g2d + i + 4));
            i32x4 ra, rb;
            ra[0] = atomicAdd(&cnt2p[d0[0] * PAD2], 1);
            ra[1] = atomicAdd(&cnt2p[d0[1] * PAD2], 1);
            ra[2] = atomicAdd(&cnt2p[d0[2] * PAD2], 1);
            ra[3] = atomicAdd(&cnt2p[d0[3] * PAD2], 1);
            rb[0] = atomicAdd(&cnt2p[d1[0] * PAD2], 1);
            rb[1] = atomicAdd(&cnt2p[d1[1] * PAD2], 1);
            rb[2] = atomicAdd(&cnt2p[d1[2] * PAD2], 1);
            rb[3] = atomicAdd(&cnt2p[d1[3] * PAD2], 1);
            nts(ra, (i32x4*)(rank2 + i));
            nts(rb, (i32x4*)(rank2 + i + 4));
        } else {
            for (; i < nnz; ++i) rank2[i] = atomicAdd(&cnt2p[g2d[i] * PAD2], 1);
        }
        return;
    }
    // ---- edge gather path: one wave per edge ----
    __shared__ int pref[17];
    lds_pref(pref, bsum1, nb1, threadIdx.x);
    const int wid  = threadIdx.x >> 6;
    const int lane = threadIdx.x & 63;
    int e = (blockIdx.x - H) * 4 + wid;
    if (e >= n_edges) return;
    const int g = lane >> 4;                      // ref slot 0..3
    const int c = lane & 15;                      // column group (cols c*8..c*8+7)
    int beg = off1[e] + pref[e >> 11];
    int end = off1[e + 1] + pref[(e + 1) >> 11];
    float a0[8] = {0, 0, 0, 0, 0, 0, 0, 0};
    float a1[8] = {0, 0, 0, 0, 0, 0, 0, 0};
    int j = beg + g;
    for (; j + 4 < end; j += 8) {                 // two refs per group per iter
        int s0 = ntl(srcs1 + j);
        int s1 = ntl(srcs1 + j + 4);
        f16x8 v0 = *(const f16x8*)(Xh + (size_t)s0 * DD + c * 8);
        f16x8 v1 = *(const f16x8*)(Xh + (size_t)s1 * DD + c * 8);
        #pragma unroll
        for (int t = 0; t < 8; ++t) { a0[t] += (float)v0[t]; a1[t] += (float)v1[t]; }
    }
    if (j < end) {
        int s = ntl(srcs1 + j);
        f16x8 v = *(const f16x8*)(Xh + (size_t)s * DD + c * 8);
        #pragma unroll
        for (int t = 0; t < 8; ++t) a0[t] += (float)v[t];
    }
    float r[8];
    #pragma unroll
    for (int t = 0; t < 8; ++t) r[t] = a0[t] + a1[t];
    #pragma unroll
    for (int t = 0; t < 8; ++t) r[t] += __shfl_xor(r[t], 16);
    #pragma unroll
    for (int t = 0; t < 8; ++t) r[t] += __shfl_xor(r[t], 32);
    if (g == 0) {
        float f = degE[e];
        f16x8 ob;
        #pragma unroll
        for (int t = 0; t < 8; ++t) ob[t] = (_Float16)(f * r[t]);
        nts(ob, (f16x8*)(XeH + (size_t)e * DD + c * 8));
    }
}

// ---------------------------------------------------------------------------
// k_ng_gemm: fused node gather + GCNII blend + GEMM.
// The gather's 205 MB of XeH reads (40x reuse per edge row) are the L2-reuse
// target: EVERYTHING else (X0, srcs2, off2, degV, out) is marked NT so XeH
// (5.12 MB) stays resident in each XCD's 4 MB L2 instead of being served by
// Infinity Cache at ~2.7 TB/s (measured round 4).
// ---------------------------------------------------------------------------
__global__ __launch_bounds__(256)
void k_ng_gemm(const _Float16* __restrict__ XeH, const int* __restrict__ off2,
               const int* __restrict__ bsum2, int nb2,
               const int* __restrict__ srcs2, const float* __restrict__ degV,
               const float* __restrict__ X0, const float* __restrict__ alphaP,
               const _Float16* __restrict__ Mh, float* __restrict__ out,
               int n_nodes) {
    __shared__ int pref[65];
    __shared__ _Float16 xi_lds[4][16 * DD];       // 4 waves x 4KB
    const int tid = threadIdx.x;
    lds_pref(pref, bsum2, nb2, tid);
    const int wid  = tid >> 6;
    const int lane = tid & 63;
    const int strip = blockIdx.x * 4 + wid;
    const int row0 = strip * 16;
    const bool live = row0 < n_nodes;
    _Float16* lbase = &xi_lds[wid][0];

    // ---- phase 1: gather 16 rows into swizzled LDS ----
    const int r16 = lane >> 2;                    // node within strip
    const int sl  = lane & 3;                     // col quarter (32 cols)
    const int row = row0 + r16;
    if (live) {
        float acc[32];
        #pragma unroll
        for (int t = 0; t < 32; ++t) acc[t] = 0.0f;
        if (row < n_nodes) {
            int beg = ntl(off2 + row) + pref[row >> 11];
            int end = ntl(off2 + row + 1) + pref[(row + 1) >> 11];
            int j = beg;
            for (; j + 4 <= end; j += 4) {        // 4 rows / 16 loads in flight
                int s0 = ntl(srcs2 + j);
                int s1 = ntl(srcs2 + j + 1);
                int s2 = ntl(srcs2 + j + 2);
                int s3 = ntl(srcs2 + j + 3);
                const _Float16* p0 = XeH + (size_t)s0 * DD + sl * 32;
                const _Float16* p1 = XeH + (size_t)s1 * DD + sl * 32;
                const _Float16* p2 = XeH + (size_t)s2 * DD + sl * 32;
                const _Float16* p3 = XeH + (size_t)s3 * DD + sl * 32;
                f16x8 u0 = *(const f16x8*)(p0);
                f16x8 u1 = *(const f16x8*)(p0 + 8);
                f16x8 u2 = *(const f16x8*)(p0 + 16);
                f16x8 u3 = *(const f16x8*)(p0 + 24);
                f16x8 v0 = *(const f16x8*)(p1);
                f16x8 v1 = *(const f16x8*)(p1 + 8);
                f16x8 v2 = *(const f16x8*)(p1 + 16);
                f16x8 v3 = *(const f16x8*)(p1 + 24);
                f16x8 w0 = *(const f16x8*)(p2);
                f16x8 w1 = *(const f16x8*)(p2 + 8);
                f16x8 w2 = *(const f16x8*)(p2 + 16);
                f16x8 w3 = *(const f16x8*)(p2 + 24);
                f16x8 y0 = *(const f16x8*)(p3);
                f16x8 y1 = *(const f16x8*)(p3 + 8);
                f16x8 y2 = *(const f16x8*)(p3 + 16);
                f16x8 y3 = *(const f16x8*)(p3 + 24);
                #pragma unroll
                for (int t = 0; t < 8; ++t) {
                    acc[t]      += ((float)u0[t] + (float)v0[t]) + ((float)w0[t] + (float)y0[t]);
                    acc[8 + t]  += ((float)u1[t] + (float)v1[t]) + ((float)w1[t] + (float)y1[t]);
                    acc[16 + t] += ((float)u2[t] + (float)v2[t]) + ((float)w2[t] + (float)y2[t]);
                    acc[24 + t] += ((float)u3[t] + (float)v3[t]) + ((float)w3[t] + (float)y3[t]);
                }
            }
            for (; j < end; ++j) {
                int s = ntl(srcs2 + j);
                const _Float16* p0 = XeH + (size_t)s * DD + sl * 32;
                f16x8 u0 = *(const f16x8*)(p0);
                f16x8 u1 = *(const f16x8*)(p0 + 8);
                f16x8 u2 = *(const f16x8*)(p0 + 16);
                f16x8 u3 = *(const f16x8*)(p0 + 24);
                #pragma unroll
                for (int t = 0; t < 8; ++t) {
                    acc[t]      += (float)u0[t];
                    acc[8 + t]  += (float)u1[t];
                    acc[16 + t] += (float)u2[t];
                    acc[24 + t] += (float)u3[t];
                }
            }
            float a = alphaP[0];
            float f = (1.0f - a) * ntl(degV + row);
            const float* x0p = X0 + (size_t)row * DD + sl * 32;
            #pragma unroll
            for (int c2 = 0; c2 < 4; ++c2) {
                f32x4 xa = ntl((const f32x4*)(x0p + c2 * 8));
                f32x4 xb = ntl((const f32x4*)(x0p + c2 * 8 + 4));
                f16x8 h;
                h[0] = (_Float16)(f * acc[c2 * 8 + 0] + a * xa[0]);
                h[1] = (_Float16)(f * acc[c2 * 8 + 1] + a * xa[1]);
                h[2] = (_Float16)(f * acc[c2 * 8 + 2] + a * xa[2]);
                h[3] = (_Float16)(f * acc[c2 * 8 + 3] + a * xa[3]);
                h[4] = (_Float16)(f * acc[c2 * 8 + 4] + a * xb[0]);
                h[5] = (_Float16)(f * acc[c2 * 8 + 5] + a * xb[1]);
                h[6] = (_Float16)(f * acc[c2 * 8 + 6] + a * xb[2]);
                h[7] = (_Float16)(f * acc[c2 * 8 + 7] + a * xb[3]);
                int byte = r16 * 256 + sl * 64 + c2 * 16;
                byte ^= (r16 & 7) << 4;            // bank swizzle
                *(f16x8*)((char*)lbase + byte) = h;
            }
        } else {
            // dead row inside live strip: zero its LDS slots
            f16x8 z = {0, 0, 0, 0, 0, 0, 0, 0};
            #pragma unroll
            for (int c2 = 0; c2 < 4; ++c2) {
                int byte = r16 * 256 + sl * 64 + c2 * 16;
                byte ^= (r16 & 7) << 4;
                *(f16x8*)((char*)lbase + byte) = z;
            }
        }
    }
    __syncthreads();
    if (!live) return;

    // ---- phase 2: MFMA strip-GEMM, A from swizzled LDS, B from M' ----
    const int m16  = lane & 15;
    const int quad = lane >> 4;
    const int kq   = quad * 8;
    f16x8 af[4];
    #pragma unroll
    for (int kf = 0; kf < 4; ++kf) {
        int byte = m16 * 256 + kf * 64 + quad * 16;
        byte ^= (m16 & 7) << 4;
        af[kf] = *(const f16x8*)((const char*)lbase + byte);
    }
    #pragma unroll
    for (int nt2 = 0; nt2 < 8; ++nt2) {
        const _Float16* mr = Mh + (size_t)(nt2 * 16 + m16) * DD + kq;
        f32x4 acc = {0.f, 0.f, 0.f, 0.f};
        #pragma unroll
        for (int kf = 0; kf < 4; ++kf) {
            f16x8 bfrag = *(const f16x8*)(mr + kf * 32);
            acc = __builtin_amdgcn_mfma_f32_16x16x32_f16(af[kf], bfrag, acc, 0, 0, 0);
        }
        const int col = nt2 * 16 + m16;
        #pragma unroll
        for (int r = 0; r < 4; ++r) {
            int orow = row0 + quad * 4 + r;
            if (orow < n_nodes)
                nts(acc[r], &out[(size_t)orow * DD + col]);
        }
    }
}

// ---------------------------------------------------------------------------
extern "C" void kernel_launch(void* const* d_in, const int* in_sizes, int n_in,
                              void* d_out, int out_size, void* d_ws, size_t ws_size,
                              hipStream_t stream) {
    const float* X     = (const float*)d_in[0];
    const float* X0    = (const float*)d_in[1];
    const float* degE  = (const float*)d_in[2];
    const float* degV  = (const float*)d_in[3];
    const float* alpha = (const float*)d_in[4];
    const float* beta  = (const float*)d_in[5];
    const float* W     = (const float*)d_in[6];
    const int*   g1s   = (const int*)d_in[7];
    const int*   g1d   = (const int*)d_in[8];
    const int*   g2s   = (const int*)d_in[9];
    const int*   g2d   = (const int*)d_in[10];
    float* out = (float*)d_out;

    const int n_nodes = in_sizes[3];        // 100000
    const int n_edges = in_sizes[2];        // 20000
    const int nnz     = in_sizes[7];        // 800000
    const int nx      = n_nodes * DD;       // 12.8M elems

    // --- workspace layout (4-byte units) ---
    // XeH (fp16 [E][128]) first; rank1/rank2 share one slot; cnt1p overlays
    // srcs1; cnt2p overlays srcs2 exactly (n_nodes*PAD2 == nnz).
    // Xh (fp16 copy of X) lives in d_out: dead after k_h2_egather, which
    // completes before k_ng_gemm writes out (stream order).
    int*   wsi   = (int*)d_ws;
    _Float16* XeH = (_Float16*)d_ws;                   // [E*128] fp16 (5.12 MB)
    size_t o     = (size_t)n_edges * DD / 2;           // words
    int*   rank1 = wsi + o;                            // [nnz]
    int*   rank2 = rank1;                              // shared slot
    o += nnz;
    int*   off1  = wsi + o;          o += n_edges + 1;
    int*   off2  = wsi + o;          o += n_nodes + 1;
    size_t srcs_base = o;
    int*   srcs1 = wsi + o;          o += nnz;
    int*   srcs2 = wsi + o;          o += nnz;
    int*   bsum  = wsi + o;          o += 128;
    _Float16* Mh = (_Float16*)(wsi + o); o += DD * DD / 2; // fp16 [128][128]
    int*   cnt1p = wsi + srcs_base;                    // [n_edges*PAD1]
    int*   cnt2p = wsi + srcs_base + nnz;              // [n_nodes*PAD2] == srcs2
    _Float16* Xh = (_Float16*)d_out;                   // fp16 [N][128] scratch

    // zero both padded counter regions (they live inside srcs1/srcs2)
    hipMemsetAsync(cnt1p, 0, 2 * (size_t)nnz * sizeof(int), stream);

    const int nb1 = (n_edges + SCAN_CHUNK - 1) / SCAN_CHUNK;   // 10
    const int nb2 = (n_nodes + SCAN_CHUNK - 1) / SCAN_CHUNK;   // 49
    const int no  = (nnz + 7) / 8;                             // octs per graph
    const int hb  = (no + 255) / 256;                          // hist blocks: 391
    const int cb  = (nx / 8 + 255) / 256;                      // conv blocks: 6250
    const int nq  = (nnz + 3) / 4;                             // quads per graph
    const int qb  = (nq + 255) / 256;                          // fill blocks

    // ---- g1 hist + prep_w + X->fp16, one grid ----
    k_hist1<<<hb + 8 + cb, 256, 0, stream>>>(g1d, cnt1p, rank1, nnz, no, hb,
                                             W, beta, Mh, X, Xh, nx);
    k_scan_blocks<<<nb1, 256, 0, stream>>>(cnt1p, off1, bsum, n_edges, PAD1);
    k_fill<<<qb, 256, 0, stream>>>(g1d, g1s, off1, rank1, bsum, nb1, srcs1, nnz);

    // ---- fused: g2 histogram rides under the wave-per-edge fp16 gather ----
    const int egb = (n_edges + 3) / 4;                         // 5000
    k_h2_egather<<<hb + egb, 256, 0, stream>>>(g2d, cnt2p, rank2, nnz, no, hb,
                                               Xh, off1, bsum, nb1,
                                               srcs1, degE, XeH, n_edges);

    // ---- g2 CSR finalize ----
    k_scan_blocks<<<nb2, 256, 0, stream>>>(cnt2p, off2, bsum + 64, n_nodes, PAD2);
    k_fill<<<qb, 256, 0, stream>>>(g2d, g2s, off2, rank2, bsum + 64, nb2, srcs2, nnz);

    // ---- fused node gather + blend + MFMA GEMM -> out ----
    const int nstrips = (n_nodes + 15) / 16;                   // 6250
    k_ng_gemm<<<(nstrips + 3) / 4, 256, 0, stream>>>(
        XeH, off2, bsum + 64, nb2, srcs2, degV, X0, alpha, Mh, out, n_nodes);
}

// Round 6
// 341.054 us; speedup vs baseline: 1.0965x; 1.0965x over previous
//
#include <hip/hip_runtime.h>

#define DD 128
#define SCAN_CHUNK 2048   // 256 threads x 8 elements per scan block
#define PAD1 16           // cnt1 stride: one counter per 64B line
#define PAD2 8            // cnt2 stride: two counters per 64B line

typedef __attribute__((ext_vector_type(8))) _Float16 f16x8;
typedef __attribute__((ext_vector_type(4))) _Float16 f16x4;
typedef __attribute__((ext_vector_type(4))) float f32x4;

// ---------------------------------------------------------------------------
// k_hist1: three block ranges, all independent:
//   [0, hb)        : histogram g1 into padded counters, capture ranks
//   [hb, hb+8)     : fold (1-b)I + b*W into fp16 M' (prep_w)
//   [hb+8, +cb)    : convert X (fp32) -> Xh (fp16)
// ---------------------------------------------------------------------------
__global__ __launch_bounds__(256)
void k_hist1(const int* __restrict__ g1d, int* __restrict__ cnt1p,
             int* __restrict__ rank1, int nnz, int no, int hb,
             const float* __restrict__ W, const float* __restrict__ betaP,
             _Float16* __restrict__ Mh,
             const float* __restrict__ X, _Float16* __restrict__ Xh, int nx) {
    const int b = blockIdx.x;
    if (b < hb) {                              // ---- hist g1 ----
        int q = b * 256 + threadIdx.x;
        if (q >= no) return;
        int i = q << 3;
        if (i + 8 <= nnz) {
            int4 d0 = *(const int4*)(g1d + i);
            int4 d1 = *(const int4*)(g1d + i + 4);
            int r0 = atomicAdd(&cnt1p[d0.x * PAD1], 1);
            int r1 = atomicAdd(&cnt1p[d0.y * PAD1], 1);
            int r2 = atomicAdd(&cnt1p[d0.z * PAD1], 1);
            int r3 = atomicAdd(&cnt1p[d0.w * PAD1], 1);
            int r4 = atomicAdd(&cnt1p[d1.x * PAD1], 1);
            int r5 = atomicAdd(&cnt1p[d1.y * PAD1], 1);
            int r6 = atomicAdd(&cnt1p[d1.z * PAD1], 1);
            int r7 = atomicAdd(&cnt1p[d1.w * PAD1], 1);
            *(int4*)(rank1 + i)     = make_int4(r0, r1, r2, r3);
            *(int4*)(rank1 + i + 4) = make_int4(r4, r5, r6, r7);
        } else {
            for (; i < nnz; ++i) rank1[i] = atomicAdd(&cnt1p[g1d[i] * PAD1], 1);
        }
        return;
    }
    if (b < hb + 8) {                          // ---- prep_w (fp16 M') ----
        int gid = (b - hb) * 256 + threadIdx.x;     // 2048 threads, 8 elems each
        if (gid >= DD * DD / 8) return;
        int c  = gid >> 4;
        int k0 = (gid & 15) << 3;
        float bb = betaP[0], ib = 1.0f - bb;
        const float* p = W + c * DD + k0;
        f32x4 lo = *(const f32x4*)p, hi = *(const f32x4*)(p + 4);
        float v[8] = {lo[0], lo[1], lo[2], lo[3], hi[0], hi[1], hi[2], hi[3]};
        f16x8 t;
        #pragma unroll
        for (int j = 0; j < 8; ++j) {
            float m = bb * v[j] + ((k0 + j) == c ? ib : 0.0f);
            t[j] = (_Float16)m;
        }
        *(f16x8*)(Mh + (size_t)c * DD + k0) = t;
        return;
    }
    // ---- X -> fp16 conversion ----
    int gid = (b - hb - 8) * 256 + threadIdx.x;
    int i = gid << 3;
    if (i + 8 <= nx) {
        f32x4 lo = *(const f32x4*)(X + i);
        f32x4 hi = *(const f32x4*)(X + i + 4);
        f16x8 t;
        t[0] = (_Float16)lo[0]; t[1] = (_Float16)lo[1];
        t[2] = (_Float16)lo[2]; t[3] = (_Float16)lo[3];
        t[4] = (_Float16)hi[0]; t[5] = (_Float16)hi[1];
        t[6] = (_Float16)hi[2]; t[7] = (_Float16)hi[3];
        *(f16x8*)(Xh + i) = t;
    } else {
        for (; i < nx; ++i) Xh[i] = (_Float16)X[i];
    }
}

// ---------------------------------------------------------------------------
// k_scan_blocks: chunk-local EXCLUSIVE scan of padded counters -> off[]
// (chunk-local values; consumers add the chunk base from bsum),
// per-chunk totals -> bsum[b]. Stores off[idx] for idx <= n so off[n] exists.
// ---------------------------------------------------------------------------
__global__ __launch_bounds__(256)
void k_scan_blocks(const int* __restrict__ cnt, int* __restrict__ off,
                   int* __restrict__ bsum, int n, int str) {
    __shared__ int sh[256];
    const int tid = threadIdx.x;
    const int base = blockIdx.x * SCAN_CHUNK + tid * 8;
    int v[8];
    int s = 0;
    #pragma unroll
    for (int j = 0; j < 8; ++j) {
        int idx = base + j;
        v[j] = (idx < n) ? cnt[(size_t)idx * str] : 0;
        s += v[j];
    }
    sh[tid] = s;
    __syncthreads();
    for (int d = 1; d < 256; d <<= 1) {
        int y = (tid >= d) ? sh[tid - d] : 0;
        __syncthreads();
        sh[tid] += y;
        __syncthreads();
    }
    int incl = sh[tid];
    int run = incl - s;
    #pragma unroll
    for (int j = 0; j < 8; ++j) {
        int idx = base + j;
        if (idx <= n) off[idx] = run;
        run += v[j];
    }
    if (tid == 255) bsum[blockIdx.x] = incl;      // chunk total (inclusive)
}

// ---------------------------------------------------------------------------
// load bsum in parallel, LDS-only serial scan (nb <= 49).
// ---------------------------------------------------------------------------
__device__ __forceinline__ void lds_pref(int* pref, const int* bsum, int nb,
                                         int tid) {
    if (tid < 64) pref[tid] = (tid < nb) ? bsum[tid] : 0;
    __syncthreads();
    if (tid == 0) {
        int run = 0;
        for (int i = 0; i < nb; ++i) { int t = pref[i]; pref[i] = run; run += t; }
        pref[nb] = run;
    }
    __syncthreads();
}

// ---------------------------------------------------------------------------
// k_fill: srcs[off[d] + pref[d>>11] + rank[i]] = src[i]. No atomics.
// ---------------------------------------------------------------------------
__global__ __launch_bounds__(256)
void k_fill(const int* __restrict__ dst, const int* __restrict__ src,
            const int* __restrict__ off, const int* __restrict__ rank,
            const int* __restrict__ bsum, int nb,
            int* __restrict__ out, int nnz) {
    __shared__ int pref[65];
    lds_pref(pref, bsum, nb, threadIdx.x);
    int q = blockIdx.x * 256 + threadIdx.x;
    int i = q << 2;
    if (i + 4 <= nnz) {
        int4 d = *(const int4*)(dst + i);
        int4 s = *(const int4*)(src + i);
        int4 r = *(const int4*)(rank + i);
        int o0 = off[d.x] + pref[d.x >> 11];
        int o1 = off[d.y] + pref[d.y >> 11];
        int o2 = off[d.z] + pref[d.z >> 11];
        int o3 = off[d.w] + pref[d.w >> 11];
        out[o0 + r.x] = s.x;
        out[o1 + r.y] = s.y;
        out[o2 + r.z] = s.z;
        out[o3 + r.w] = s.w;
    } else {
        for (; i < nnz; ++i)
            out[off[dst[i]] + pref[dst[i] >> 11] + rank[i]] = src[i];
    }
}

// ---------------------------------------------------------------------------
// k_h2_egather: fused kernel.
//   blocks [0,H):  histogram g2 (atomic/latency-bound, no upstream deps)
//   blocks [H,..): edge gather, one wave per edge: lanes = 4 ref slots x 16
//                  column chunks (16B each -> dense 64B lines). 4 refs in
//                  flight per slot (16 rows/wave); shfl_xor(16/32) reduce.
// ---------------------------------------------------------------------------
__global__ __launch_bounds__(256)
void k_h2_egather(const int* __restrict__ g2d, int* __restrict__ cnt2p,
                  int* __restrict__ rank2, int nnz, int no, int H,
                  const _Float16* __restrict__ Xh, const int* __restrict__ off1,
                  const int* __restrict__ bsum1, int nb1,
                  const int* __restrict__ srcs1, const float* __restrict__ degE,
                  _Float16* __restrict__ XeH, int n_edges) {
    if (blockIdx.x < H) {                         // ---- hist g2 path ----
        int q = blockIdx.x * 256 + threadIdx.x;
        if (q >= no) return;
        int i = q << 3;
        if (i + 8 <= nnz) {
            int4 d0 = *(const int4*)(g2d + i);
            int4 d1 = *(const int4*)(g2d + i + 4);
            int r0 = atomicAdd(&cnt2p[d0.x * PAD2], 1);
            int r1 = atomicAdd(&cnt2p[d0.y * PAD2], 1);
            int r2 = atomicAdd(&cnt2p[d0.z * PAD2], 1);
            int r3 = atomicAdd(&cnt2p[d0.w * PAD2], 1);
            int r4 = atomicAdd(&cnt2p[d1.x * PAD2], 1);
            int r5 = atomicAdd(&cnt2p[d1.y * PAD2], 1);
            int r6 = atomicAdd(&cnt2p[d1.z * PAD2], 1);
            int r7 = atomicAdd(&cnt2p[d1.w * PAD2], 1);
            *(int4*)(rank2 + i)     = make_int4(r0, r1, r2, r3);
            *(int4*)(rank2 + i + 4) = make_int4(r4, r5, r6, r7);
        } else {
            for (; i < nnz; ++i) rank2[i] = atomicAdd(&cnt2p[g2d[i] * PAD2], 1);
        }
        return;
    }
    // ---- edge gather path: one wave per edge ----
    __shared__ int pref[17];
    lds_pref(pref, bsum1, nb1, threadIdx.x);
    const int wid  = threadIdx.x >> 6;
    const int lane = threadIdx.x & 63;
    int e = (blockIdx.x - H) * 4 + wid;
    if (e >= n_edges) return;
    const int g = lane >> 4;                      // ref slot 0..3
    const int c = lane & 15;                      // column chunk (cols c*8..c*8+7)
    int beg = off1[e] + pref[e >> 11];
    int end = off1[e + 1] + pref[(e + 1) >> 11];
    float a0[8] = {0, 0, 0, 0, 0, 0, 0, 0};
    float a1[8] = {0, 0, 0, 0, 0, 0, 0, 0};
    int j = beg + g;
    for (; j + 12 < end; j += 16) {               // 4 refs in flight per slot
        int s0 = srcs1[j];
        int s1 = srcs1[j + 4];
        int s2 = srcs1[j + 8];
        int s3 = srcs1[j + 12];
        f16x8 v0 = *(const f16x8*)(Xh + (size_t)s0 * DD + c * 8);
        f16x8 v1 = *(const f16x8*)(Xh + (size_t)s1 * DD + c * 8);
        f16x8 v2 = *(const f16x8*)(Xh + (size_t)s2 * DD + c * 8);
        f16x8 v3 = *(const f16x8*)(Xh + (size_t)s3 * DD + c * 8);
        #pragma unroll
        for (int t = 0; t < 8; ++t) {
            a0[t] += (float)v0[t] + (float)v2[t];
            a1[t] += (float)v1[t] + (float)v3[t];
        }
    }
    for (; j < end; j += 4) {
        int s = srcs1[j];
        f16x8 v = *(const f16x8*)(Xh + (size_t)s * DD + c * 8);
        #pragma unroll
        for (int t = 0; t < 8; ++t) a0[t] += (float)v[t];
    }
    float r[8];
    #pragma unroll
    for (int t = 0; t < 8; ++t) r[t] = a0[t] + a1[t];
    #pragma unroll
    for (int t = 0; t < 8; ++t) r[t] += __shfl_xor(r[t], 16);
    #pragma unroll
    for (int t = 0; t < 8; ++t) r[t] += __shfl_xor(r[t], 32);
    if (g == 0) {
        float f = degE[e];
        f16x8 ob;
        #pragma unroll
        for (int t = 0; t < 8; ++t) ob[t] = (_Float16)(f * r[t]);
        *(f16x8*)(XeH + (size_t)e * DD + c * 8) = ob;
    }
}

// ---------------------------------------------------------------------------
// k_ng_gemm: fused node gather + GCNII blend + GEMM. Block = one 16-row strip.
// Phase 1 (dense-line mapping): wave = 4 nodes x 16 col-chunks of 16B —
// consecutive lanes cover consecutive 16B of the SAME row, so a wave load
// instruction touches 16 fully-used 64B lines (was 64 quarter-used lines:
// the round-4/5 bottleneck). 4 refs in flight per node. Blend, swizzled LDS.
// Phase 2: 4 waves split the 8 N-tiles of the strip's MFMA.
// ---------------------------------------------------------------------------
__global__ __launch_bounds__(256)
void k_ng_gemm(const _Float16* __restrict__ XeH, const int* __restrict__ off2,
               const int* __restrict__ bsum2, int nb2,
               const int* __restrict__ srcs2, const float* __restrict__ degV,
               const float* __restrict__ X0, const float* __restrict__ alphaP,
               const _Float16* __restrict__ Mh, float* __restrict__ out,
               int n_nodes) {
    __shared__ int pref[65];
    __shared__ _Float16 xi_lds[16 * DD];          // one strip, 4 KB
    const int tid = threadIdx.x;
    lds_pref(pref, bsum2, nb2, tid);
    const int wid  = tid >> 6;
    const int lane = tid & 63;
    const int g    = lane >> 4;                   // node slot in wave (0..3)
    const int c    = lane & 15;                   // 16B column chunk
    const int r16  = wid * 4 + g;                 // row within strip
    const int row0 = blockIdx.x * 16;
    const int row  = row0 + r16;

    // ---- phase 1: gather one row per 16 lanes into swizzled LDS ----
    {
        float a0[8] = {0, 0, 0, 0, 0, 0, 0, 0};
        float a1[8] = {0, 0, 0, 0, 0, 0, 0, 0};
        if (row < n_nodes) {
            int beg = off2[row] + pref[row >> 11];
            int end = off2[row + 1] + pref[(row + 1) >> 11];
            int j = beg;
            for (; j + 3 < end; j += 4) {         // 4 rows in flight per node
                int s0 = srcs2[j];
                int s1 = srcs2[j + 1];
                int s2 = srcs2[j + 2];
                int s3 = srcs2[j + 3];
                f16x8 v0 = *(const f16x8*)(XeH + (size_t)s0 * DD + c * 8);
                f16x8 v1 = *(const f16x8*)(XeH + (size_t)s1 * DD + c * 8);
                f16x8 v2 = *(const f16x8*)(XeH + (size_t)s2 * DD + c * 8);
                f16x8 v3 = *(const f16x8*)(XeH + (size_t)s3 * DD + c * 8);
                #pragma unroll
                for (int t = 0; t < 8; ++t) {
                    a0[t] += (float)v0[t] + (float)v2[t];
                    a1[t] += (float)v1[t] + (float)v3[t];
                }
            }
            for (; j < end; ++j) {
                int s = srcs2[j];
                f16x8 v = *(const f16x8*)(XeH + (size_t)s * DD + c * 8);
                #pragma unroll
                for (int t = 0; t < 8; ++t) a0[t] += (float)v[t];
            }
            float a = alphaP[0];
            float f = (1.0f - a) * degV[row];
            const float* x0p = X0 + (size_t)row * DD + c * 8;
            f32x4 xa = *(const f32x4*)(x0p);
            f32x4 xb = *(const f32x4*)(x0p + 4);
            f16x8 h;
            h[0] = (_Float16)(f * (a0[0] + a1[0]) + a * xa[0]);
            h[1] = (_Float16)(f * (a0[1] + a1[1]) + a * xa[1]);
            h[2] = (_Float16)(f * (a0[2] + a1[2]) + a * xa[2]);
            h[3] = (_Float16)(f * (a0[3] + a1[3]) + a * xa[3]);
            h[4] = (_Float16)(f * (a0[4] + a1[4]) + a * xb[0]);
            h[5] = (_Float16)(f * (a0[5] + a1[5]) + a * xb[1]);
            h[6] = (_Float16)(f * (a0[6] + a1[6]) + a * xb[2]);
            h[7] = (_Float16)(f * (a0[7] + a1[7]) + a * xb[3]);
            int byte = r16 * 256 + c * 16;
            byte ^= (r16 & 7) << 4;               // bank swizzle
            *(f16x8*)((char*)xi_lds + byte) = h;
        } else {
            f16x8 z = {0, 0, 0, 0, 0, 0, 0, 0};
            int byte = r16 * 256 + c * 16;
            byte ^= (r16 & 7) << 4;
            *(f16x8*)((char*)xi_lds + byte) = z;
        }
    }
    __syncthreads();

    // ---- phase 2: MFMA strip-GEMM; wave w handles N-tiles {2w, 2w+1} ----
    const int m16  = lane & 15;
    const int quad = lane >> 4;
    const int kq   = quad * 8;
    f16x8 af[4];
    #pragma unroll
    for (int kf = 0; kf < 4; ++kf) {
        int byte = m16 * 256 + kf * 64 + quad * 16;
        byte ^= (m16 & 7) << 4;
        af[kf] = *(const f16x8*)((const char*)xi_lds + byte);
    }
    #pragma unroll
    for (int u = 0; u < 2; ++u) {
        const int nt2 = wid * 2 + u;
        const _Float16* mr = Mh + (size_t)(nt2 * 16 + m16) * DD + kq;
        f32x4 acc = {0.f, 0.f, 0.f, 0.f};
        #pragma unroll
        for (int kf = 0; kf < 4; ++kf) {
            f16x8 bfrag = *(const f16x8*)(mr + kf * 32);
            acc = __builtin_amdgcn_mfma_f32_16x16x32_f16(af[kf], bfrag, acc, 0, 0, 0);
        }
        const int col = nt2 * 16 + m16;
        #pragma unroll
        for (int r = 0; r < 4; ++r) {
            int orow = row0 + quad * 4 + r;
            if (orow < n_nodes)
                out[(size_t)orow * DD + col] = acc[r];
        }
    }
}

// ---------------------------------------------------------------------------
extern "C" void kernel_launch(void* const* d_in, const int* in_sizes, int n_in,
                              void* d_out, int out_size, void* d_ws, size_t ws_size,
                              hipStream_t stream) {
    const float* X     = (const float*)d_in[0];
    const float* X0    = (const float*)d_in[1];
    const float* degE  = (const float*)d_in[2];
    const float* degV  = (const float*)d_in[3];
    const float* alpha = (const float*)d_in[4];
    const float* beta  = (const float*)d_in[5];
    const float* W     = (const float*)d_in[6];
    const int*   g1s   = (const int*)d_in[7];
    const int*   g1d   = (const int*)d_in[8];
    const int*   g2s   = (const int*)d_in[9];
    const int*   g2d   = (const int*)d_in[10];
    float* out = (float*)d_out;

    const int n_nodes = in_sizes[3];        // 100000
    const int n_edges = in_sizes[2];        // 20000
    const int nnz     = in_sizes[7];        // 800000
    const int nx      = n_nodes * DD;       // 12.8M elems

    // --- workspace layout (4-byte units) ---
    // XeH (fp16 [E][128]) first; rank1/rank2 share one slot; cnt1p overlays
    // srcs1; cnt2p overlays srcs2 exactly (n_nodes*PAD2 == nnz).
    // Xh (fp16 copy of X) lives in d_out: dead after k_h2_egather, which
    // completes before k_ng_gemm writes out (stream order).
    int*   wsi   = (int*)d_ws;
    _Float16* XeH = (_Float16*)d_ws;                   // [E*128] fp16 (5.12 MB)
    size_t o     = (size_t)n_edges * DD / 2;           // words
    int*   rank1 = wsi + o;                            // [nnz]
    int*   rank2 = rank1;                              // shared slot
    o += nnz;
    int*   off1  = wsi + o;          o += n_edges + 1;
    int*   off2  = wsi + o;          o += n_nodes + 1;
    size_t srcs_base = o;
    int*   srcs1 = wsi + o;          o += nnz;
    int*   srcs2 = wsi + o;          o += nnz;
    int*   bsum  = wsi + o;          o += 128;
    _Float16* Mh = (_Float16*)(wsi + o); o += DD * DD / 2; // fp16 [128][128]
    int*   cnt1p = wsi + srcs_base;                    // [n_edges*PAD1]
    int*   cnt2p = wsi + srcs_base + nnz;              // [n_nodes*PAD2] == srcs2
    _Float16* Xh = (_Float16*)d_out;                   // fp16 [N][128] scratch

    // zero both padded counter regions (they live inside srcs1/srcs2)
    hipMemsetAsync(cnt1p, 0, 2 * (size_t)nnz * sizeof(int), stream);

    const int nb1 = (n_edges + SCAN_CHUNK - 1) / SCAN_CHUNK;   // 10
    const int nb2 = (n_nodes + SCAN_CHUNK - 1) / SCAN_CHUNK;   // 49
    const int no  = (nnz + 7) / 8;                             // octs per graph
    const int hb  = (no + 255) / 256;                          // hist blocks: 391
    const int cb  = (nx / 8 + 255) / 256;                      // conv blocks: 6250
    const int nq  = (nnz + 3) / 4;                             // quads per graph
    const int qb  = (nq + 255) / 256;                          // fill blocks

    // ---- g1 hist + prep_w + X->fp16, one grid ----
    k_hist1<<<hb + 8 + cb, 256, 0, stream>>>(g1d, cnt1p, rank1, nnz, no, hb,
                                             W, beta, Mh, X, Xh, nx);
    k_scan_blocks<<<nb1, 256, 0, stream>>>(cnt1p, off1, bsum, n_edges, PAD1);
    k_fill<<<qb, 256, 0, stream>>>(g1d, g1s, off1, rank1, bsum, nb1, srcs1, nnz);

    // ---- fused: g2 histogram rides under the wave-per-edge fp16 gather ----
    const int egb = (n_edges + 3) / 4;                         // 5000
    k_h2_egather<<<hb + egb, 256, 0, stream>>>(g2d, cnt2p, rank2, nnz, no, hb,
                                               Xh, off1, bsum, nb1,
                                               srcs1, degE, XeH, n_edges);

    // ---- g2 CSR finalize ----
    k_scan_blocks<<<nb2, 256, 0, stream>>>(cnt2p, off2, bsum + 64, n_nodes, PAD2);
    k_fill<<<qb, 256, 0, stream>>>(g2d, g2s, off2, rank2, bsum + 64, nb2, srcs2, nnz);

    // ---- fused node gather + blend + MFMA GEMM -> out (one strip/block) ----
    const int nstrips = (n_nodes + 15) / 16;                   // 6250
    k_ng_gemm<<<nstrips, 256, 0, stream>>>(
        XeH, off2, bsum + 64, nb2, srcs2, degV, X0, alpha, Mh, out, n_nodes);
}